// Round 1
// baseline (806.733 us; speedup 1.0000x reference)
//
#include <hip/hip_runtime.h>
#include <hip/hip_bf16.h>
#include <stdint.h>

#define B_  4
#define T_  8192
#define H_  1024
#define NH_ 16
#define D_  64
#define BT_ (B_*T_)

typedef __attribute__((ext_vector_type(8))) __bf16 bf16x8;
typedef __attribute__((ext_vector_type(4))) __bf16 bf16x4;
typedef __attribute__((ext_vector_type(4))) float  f32x4;

__device__ __forceinline__ float phi_f(float x) {
    return x > 0.0f ? x + 1.0f : __expf(x);
}

__device__ __forceinline__ void async_copy16(const void* g, void* l) {
    __builtin_amdgcn_global_load_lds(
        (const __attribute__((address_space(1))) uint32_t*)g,
        (__attribute__((address_space(3))) uint32_t*)l, 16, 0, 0);
}

// ---------------------------------------------------------------------------
// Weight fp32 -> bf16 conversion (1M elems per W)
// ---------------------------------------------------------------------------
__global__ void wconv(const float* __restrict__ src, __bf16* __restrict__ dst) {
    int i = (blockIdx.x * 256 + threadIdx.x) * 4;
    float4 v = *(const float4*)(src + i);
    bf16x4 o;
    o[0] = (__bf16)v.x; o[1] = (__bf16)v.y; o[2] = (__bf16)v.z; o[3] = (__bf16)v.w;
    *(bf16x4*)(dst + i) = o;
}

// ---------------------------------------------------------------------------
// Projection GEMM: Out[m][n] = epi( sum_k A[m][k] * W[n][k] ), bf16 out.
// A fp32 (register-staged + converted), W bf16 (global_load_lds, pre-swizzled
// source so XOR-swizzled LDS reads are conflict-free).
// EPI: 0 = phi (Q), 1 = phi*mask (K), 2 = mask (V)
// 128x128 tile, BK=64, 256 threads (4 waves, 2x2), 16x16x32 bf16 MFMA.
// ---------------------------------------------------------------------------
template<int EPI>
__global__ __launch_bounds__(256, 2)
void proj_gemm(const float* __restrict__ A, const __bf16* __restrict__ Wb,
               const float* __restrict__ mask, __bf16* __restrict__ Out)
{
    const int bn = blockIdx.x * 128;
    const int bm = blockIdx.y * 128;
    const int tid  = threadIdx.x;
    const int lane = tid & 63;
    const int wid  = tid >> 6;
    const int wm = wid >> 1, wn = wid & 1;

    __shared__ __bf16 Al[128 * 72];   // padded rows: 144 B stride (bank-spread)
    __shared__ __bf16 Bl[128 * 64];   // linear 128 B rows, XOR-swizzled content

    f32x4 acc[4][4];
    #pragma unroll
    for (int i = 0; i < 4; ++i)
        #pragma unroll
        for (int j = 0; j < 4; ++j) acc[i][j] = (f32x4)0.0f;

    // A staging: thread covers row ar, 32-elem half
    const int ar = tid >> 1;
    const int ah = (tid & 1) * 32;
    const float* aptr = A + (size_t)(bm + ar) * H_ + ah;
    char* alw = (char*)Al + ar * 144 + ah * 2;

    // B staging (global_load_lds): lane covers dest row bsn(+issue*32), 16B seg bsc
    const int bsn = wid * 8 + (lane >> 3);
    const int bsc = (lane & 7) * 16;

    for (int k0 = 0; k0 < H_; k0 += 64) {
        // --- stage B tile (16 KB) via async copy, source pre-swizzled ---
        #pragma unroll
        for (int issue = 0; issue < 4; ++issue) {
            int n = issue * 32 + bsn;
            int csw = bsc ^ ((n & 7) << 4);
            const char* src = (const char*)(Wb + (size_t)(bn + n) * H_ + k0) + csw;
            char* dst = (char*)Bl + issue * 4096 + wid * 1024;  // wave-uniform base
            async_copy16(src, dst);
        }
        // --- stage A tile: 8 x float4 -> 32 bf16 -> 4 x ds_write_b128 ---
        {
            const float* ap = aptr + k0;
            float4 av[8];
            #pragma unroll
            for (int i = 0; i < 8; ++i) av[i] = ((const float4*)ap)[i];
            #pragma unroll
            for (int j = 0; j < 4; ++j) {
                float4 x = av[2*j], y = av[2*j+1];
                bf16x8 t;
                t[0]=(__bf16)x.x; t[1]=(__bf16)x.y; t[2]=(__bf16)x.z; t[3]=(__bf16)x.w;
                t[4]=(__bf16)y.x; t[5]=(__bf16)y.y; t[6]=(__bf16)y.z; t[7]=(__bf16)y.w;
                *(bf16x8*)(alw + j * 16) = t;
            }
        }
        __syncthreads();   // drains vmcnt (global_load_lds) + lgkmcnt
        // --- MFMA: 2 k-steps of 32 ---
        #pragma unroll
        for (int ks = 0; ks < 2; ++ks) {
            bf16x8 afr[4], bfr[4];
            #pragma unroll
            for (int mi = 0; mi < 4; ++mi) {
                int r = wm * 64 + mi * 16 + (lane & 15);
                afr[mi] = *(const bf16x8*)((const char*)Al + r * 144 + ks * 64 + (lane >> 4) * 16);
            }
            #pragma unroll
            for (int ni = 0; ni < 4; ++ni) {
                int r  = wn * 64 + ni * 16 + (lane & 15);
                int cb = (ks * 64 + (lane >> 4) * 16) ^ ((r & 7) << 4);
                bfr[ni] = *(const bf16x8*)((const char*)Bl + r * 128 + cb);
            }
            #pragma unroll
            for (int mi = 0; mi < 4; ++mi)
                #pragma unroll
                for (int ni = 0; ni < 4; ++ni)
                    acc[mi][ni] = __builtin_amdgcn_mfma_f32_16x16x32_bf16(
                        afr[mi], bfr[ni], acc[mi][ni], 0, 0, 0);
        }
        __syncthreads();
    }
    // --- epilogue: C row = (lane>>4)*4 + j, col = lane&15 ---
    const int gm0 = bm + wm * 64;
    const int gn0 = bn + wn * 64 + (lane & 15);
    #pragma unroll
    for (int mi = 0; mi < 4; ++mi) {
        #pragma unroll
        for (int j = 0; j < 4; ++j) {
            int gm = gm0 + mi * 16 + (lane >> 4) * 4 + j;
            float mv = 1.0f;
            if (EPI >= 1) mv = mask[gm];
            __bf16* op = Out + (size_t)gm * H_ + gn0;
            #pragma unroll
            for (int ni = 0; ni < 4; ++ni) {
                float v = acc[mi][ni][j];
                if (EPI == 0)      v = phi_f(v);
                else if (EPI == 1) v = phi_f(v) * mv;
                else               v = v * mv;
                op[ni * 16] = (__bf16)v;
            }
        }
    }
}

// ---------------------------------------------------------------------------
// Final GEMM: out[m][n] = sum_k An[m][k] * Wo[n][k], fp32 out, both bf16 in.
// Both operands via global_load_lds with pre-swizzled sources.
// ---------------------------------------------------------------------------
__global__ __launch_bounds__(256, 2)
void final_gemm(const __bf16* __restrict__ A, const __bf16* __restrict__ Wb,
                float* __restrict__ Out)
{
    const int bn = blockIdx.x * 128;
    const int bm = blockIdx.y * 128;
    const int tid  = threadIdx.x;
    const int lane = tid & 63;
    const int wid  = tid >> 6;
    const int wm = wid >> 1, wn = wid & 1;

    __shared__ __bf16 Al[128 * 64];
    __shared__ __bf16 Bl[128 * 64];

    f32x4 acc[4][4];
    #pragma unroll
    for (int i = 0; i < 4; ++i)
        #pragma unroll
        for (int j = 0; j < 4; ++j) acc[i][j] = (f32x4)0.0f;

    const int sn = wid * 8 + (lane >> 3);
    const int sc = (lane & 7) * 16;

    for (int k0 = 0; k0 < H_; k0 += 64) {
        #pragma unroll
        for (int issue = 0; issue < 4; ++issue) {
            int n = issue * 32 + sn;
            int csw = sc ^ ((n & 7) << 4);
            async_copy16((const char*)(A  + (size_t)(bm + n) * H_ + k0) + csw,
                         (char*)Al + issue * 4096 + wid * 1024);
            async_copy16((const char*)(Wb + (size_t)(bn + n) * H_ + k0) + csw,
                         (char*)Bl + issue * 4096 + wid * 1024);
        }
        __syncthreads();
        #pragma unroll
        for (int ks = 0; ks < 2; ++ks) {
            bf16x8 afr[4], bfr[4];
            #pragma unroll
            for (int mi = 0; mi < 4; ++mi) {
                int r  = wm * 64 + mi * 16 + (lane & 15);
                int cb = (ks * 64 + (lane >> 4) * 16) ^ ((r & 7) << 4);
                afr[mi] = *(const bf16x8*)((const char*)Al + r * 128 + cb);
            }
            #pragma unroll
            for (int ni = 0; ni < 4; ++ni) {
                int r  = wn * 64 + ni * 16 + (lane & 15);
                int cb = (ks * 64 + (lane >> 4) * 16) ^ ((r & 7) << 4);
                bfr[ni] = *(const bf16x8*)((const char*)Bl + r * 128 + cb);
            }
            #pragma unroll
            for (int mi = 0; mi < 4; ++mi)
                #pragma unroll
                for (int ni = 0; ni < 4; ++ni)
                    acc[mi][ni] = __builtin_amdgcn_mfma_f32_16x16x32_bf16(
                        afr[mi], bfr[ni], acc[mi][ni], 0, 0, 0);
        }
        __syncthreads();
    }
    const int gm0 = bm + wm * 64;
    const int gn0 = bn + wn * 64 + (lane & 15);
    #pragma unroll
    for (int mi = 0; mi < 4; ++mi)
        #pragma unroll
        for (int j = 0; j < 4; ++j) {
            int gm = gm0 + mi * 16 + (lane >> 4) * 4 + j;
            float* op = Out + (size_t)gm * H_ + gn0;
            #pragma unroll
            for (int ni = 0; ni < 4; ++ni)
                op[ni * 16] = acc[mi][ni][j];
        }
}

// ---------------------------------------------------------------------------
// KV[bh][dk][dv] += sum_t K[t,dk]*V[t,dv] ; Ksum[bh][dk] += sum_t K[t,dk]
// split-K over t (8 chunks of 1024), fp32 atomics into pre-zeroed buffers.
// Thread owns a 4x4 (dk,dv) patch; K reads broadcast, V reads conflict-free.
// ---------------------------------------------------------------------------
__global__ __launch_bounds__(256, 4)
void kv_kernel(const __bf16* __restrict__ Kb, const __bf16* __restrict__ Vb,
               float* __restrict__ KV, float* __restrict__ Ksum)
{
    const int bh = blockIdx.y;
    const int b = bh >> 4, h = bh & 15;
    const int tid = threadIdx.x;
    const int dkq = tid >> 4, dvq = tid & 15;
    __shared__ __bf16 Kt[64][72];
    __shared__ __bf16 Vt[64][72];
    float acc[4][4];
    #pragma unroll
    for (int i = 0; i < 4; ++i)
        #pragma unroll
        for (int j = 0; j < 4; ++j) acc[i][j] = 0.0f;
    float ks[4] = {0.0f, 0.0f, 0.0f, 0.0f};

    const int r = tid >> 2, part = tid & 3;
    const size_t base = ((size_t)b * T_ + (size_t)blockIdx.x * 1024) * H_
                        + h * 64 + part * 16;
    for (int it = 0; it < 16; ++it) {
        const size_t rowoff = base + (size_t)(it * 64 + r) * H_;
        *(bf16x8*)&Kt[r][part*16]     = *(const bf16x8*)(Kb + rowoff);
        *(bf16x8*)&Kt[r][part*16 + 8] = *(const bf16x8*)(Kb + rowoff + 8);
        *(bf16x8*)&Vt[r][part*16]     = *(const bf16x8*)(Vb + rowoff);
        *(bf16x8*)&Vt[r][part*16 + 8] = *(const bf16x8*)(Vb + rowoff + 8);
        __syncthreads();
        #pragma unroll 4
        for (int tt = 0; tt < 64; ++tt) {
            bf16x4 k4 = *(const bf16x4*)&Kt[tt][dkq * 4];
            bf16x4 v4 = *(const bf16x4*)&Vt[tt][dvq * 4];
            float kx[4], vx[4];
            #pragma unroll
            for (int i = 0; i < 4; ++i) { kx[i] = (float)k4[i]; vx[i] = (float)v4[i]; }
            #pragma unroll
            for (int i = 0; i < 4; ++i) {
                ks[i] += kx[i];
                #pragma unroll
                for (int j = 0; j < 4; ++j) acc[i][j] += kx[i] * vx[j];
            }
        }
        __syncthreads();
    }
    float* kvp = KV + (size_t)bh * 4096;
    #pragma unroll
    for (int i = 0; i < 4; ++i)
        #pragma unroll
        for (int j = 0; j < 4; ++j)
            atomicAdd(&kvp[(dkq*4 + i) * 64 + dvq*4 + j], acc[i][j]);
    if (dvq == 0) {
        #pragma unroll
        for (int i = 0; i < 4; ++i)
            atomicAdd(&Ksum[bh * 64 + dkq*4 + i], ks[i]);
    }
}

// KV fp32 [bh][dk][dv] -> KVT bf16 [bh][dv][dk] (transposed for MFMA B-frags)
__global__ void kvt_kernel(const float* __restrict__ KV, __bf16* __restrict__ KVT) {
    int bh = blockIdx.x, tid = threadIdx.x;
    const float* s = KV + (size_t)bh * 4096;
    __bf16* d = KVT + (size_t)bh * 4096;
    for (int i = tid; i < 4096; i += 256) {
        int dk = i >> 6, dv = i & 63;
        d[dv * 64 + dk] = (__bf16)s[i];
    }
}

// ---------------------------------------------------------------------------
// attn: On[b,t,h*64+dv] = (sum_dk Qphi[t,dk]*KV[dk,dv]) / (Qphi[t,:].Ksum + 1e-6)
// per block: one (b,h), 256 tokens; MFMA over K=64; denom fp32 cooperative.
// ---------------------------------------------------------------------------
__global__ __launch_bounds__(256, 2)
void attn_kernel(const __bf16* __restrict__ Qb, const __bf16* __restrict__ KVT,
                 const float* __restrict__ Ksum, __bf16* __restrict__ On)
{
    const int bh = blockIdx.y;
    const int b = bh >> 4, h = bh & 15;
    const int tc = blockIdx.x;
    const int tid = threadIdx.x, lane = tid & 63, wid = tid >> 6;
    __shared__ __bf16 kvl[64][72];
    __shared__ float dinv[256];

    {   // stage KVT tile (64x64 bf16) into padded LDS
        const int r = tid >> 2, part = tid & 3;
        const __bf16* src = KVT + (size_t)bh * 4096 + r * 64 + part * 16;
        *(bf16x8*)&kvl[r][part*16]     = *(const bf16x8*)src;
        *(bf16x8*)&kvl[r][part*16 + 8] = *(const bf16x8*)(src + 8);
    }
    {   // per-token denominator (fp32)
        const int t = tc * 256 + tid;
        const __bf16* qp = Qb + ((size_t)b * T_ + t) * H_ + h * 64;
        const float* kp = Ksum + bh * 64;
        float s = 0.0f;
        #pragma unroll
        for (int i = 0; i < 8; ++i) {
            bf16x8 qv = *(const bf16x8*)(qp + i * 8);
            #pragma unroll
            for (int j = 0; j < 8; ++j) s += (float)qv[j] * kp[i*8 + j];
        }
        dinv[tid] = 1.0f / (s + 1e-6f);
    }
    __syncthreads();

    f32x4 acc[4][4];
    #pragma unroll
    for (int i = 0; i < 4; ++i)
        #pragma unroll
        for (int j = 0; j < 4; ++j) acc[i][j] = (f32x4)0.0f;

    const int t0 = tc * 256 + wid * 64;
    #pragma unroll
    for (int ks = 0; ks < 2; ++ks) {
        bf16x8 afr[4], bfr[4];
        #pragma unroll
        for (int mi = 0; mi < 4; ++mi) {
            int t = t0 + mi * 16 + (lane & 15);
            afr[mi] = *(const bf16x8*)(Qb + ((size_t)b * T_ + t) * H_ + h * 64
                                       + ks * 32 + (lane >> 4) * 8);
        }
        #pragma unroll
        for (int ni = 0; ni < 4; ++ni) {
            int dv = ni * 16 + (lane & 15);
            bfr[ni] = *(const bf16x8*)&kvl[dv][ks * 32 + (lane >> 4) * 8];
        }
        #pragma unroll
        for (int mi = 0; mi < 4; ++mi)
            #pragma unroll
            for (int ni = 0; ni < 4; ++ni)
                acc[mi][ni] = __builtin_amdgcn_mfma_f32_16x16x32_bf16(
                    afr[mi], bfr[ni], acc[mi][ni], 0, 0, 0);
    }
    #pragma unroll
    for (int mi = 0; mi < 4; ++mi)
        #pragma unroll
        for (int j = 0; j < 4; ++j) {
            int lt = wid * 64 + mi * 16 + (lane >> 4) * 4 + j;
            float z = dinv[lt];
            int t = tc * 256 + lt;
            __bf16* op = On + ((size_t)b * T_ + t) * H_ + h * 64 + (lane & 15);
            #pragma unroll
            for (int ni = 0; ni < 4; ++ni)
                op[ni * 16] = (__bf16)(acc[mi][ni][j] * z);
        }
}

// ---------------------------------------------------------------------------
extern "C" void kernel_launch(void* const* d_in, const int* in_sizes, int n_in,
                              void* d_out, int out_size, void* d_ws, size_t ws_size,
                              hipStream_t stream) {
    (void)in_sizes; (void)n_in; (void)out_size; (void)ws_size;
    const float* q    = (const float*)d_in[0];
    const float* k    = (const float*)d_in[1];
    const float* v    = (const float*)d_in[2];
    const float* mask = (const float*)d_in[3];
    const float* Wq   = (const float*)d_in[4];
    const float* Wk   = (const float*)d_in[5];
    const float* Wv   = (const float*)d_in[6];
    const float* Wo   = (const float*)d_in[7];
    float* out = (float*)d_out;

    char* ws = (char*)d_ws;
    const size_t WELEM = (size_t)H_ * H_;      // 1 Mi elems
    const size_t PELEM = (size_t)BT_ * H_;     // 32 Mi elems
    __bf16* Wqb = (__bf16*)ws;
    __bf16* Wkb = Wqb + WELEM;
    __bf16* Wvb = Wkb + WELEM;
    __bf16* Wob = Wvb + WELEM;
    __bf16* Qb  = Wob + WELEM;
    __bf16* Kb  = Qb + PELEM;
    __bf16* Vb  = Kb + PELEM;
    __bf16* An  = Vb + PELEM;
    float*  KV  = (float*)(An + PELEM);
    float*  Ks  = KV + (size_t)B_ * NH_ * D_ * D_;
    __bf16* KVT = (__bf16*)(Ks + (size_t)B_ * NH_ * D_);
    // total ws use: ~278.4 MB

    hipMemsetAsync(KV, 0, ((size_t)B_*NH_*D_*D_ + (size_t)B_*NH_*D_) * sizeof(float), stream);

    wconv<<<1024, 256, 0, stream>>>(Wq, Wqb);
    wconv<<<1024, 256, 0, stream>>>(Wk, Wkb);
    wconv<<<1024, 256, 0, stream>>>(Wv, Wvb);
    wconv<<<1024, 256, 0, stream>>>(Wo, Wob);

    dim3 gg(H_/128, BT_/128);   // (8, 256)
    proj_gemm<0><<<gg, 256, 0, stream>>>(q, Wqb, mask, Qb);
    proj_gemm<1><<<gg, 256, 0, stream>>>(k, Wkb, mask, Kb);
    proj_gemm<2><<<gg, 256, 0, stream>>>(v, Wvb, mask, Vb);

    kv_kernel<<<dim3(T_/1024, B_*NH_), 256, 0, stream>>>(Kb, Vb, KV, Ks);
    kvt_kernel<<<B_*NH_, 256, 0, stream>>>(KV, KVT);
    attn_kernel<<<dim3(T_/256, B_*NH_), 256, 0, stream>>>(Qb, KVT, Ks, An);
    final_gemm<<<gg, 256, 0, stream>>>(An, Wob, out);
}

// Round 2
// 558.593 us; speedup vs baseline: 1.4442x; 1.4442x over previous
//
#include <hip/hip_runtime.h>
#include <hip/hip_bf16.h>
#include <stdint.h>

#define B_  4
#define T_  8192
#define H_  1024
#define NH_ 16
#define D_  64
#define BT_ (B_*T_)

typedef __attribute__((ext_vector_type(8))) __bf16 bf16x8;
typedef __attribute__((ext_vector_type(4))) __bf16 bf16x4;
typedef __attribute__((ext_vector_type(4))) float  f32x4;

__device__ __forceinline__ float phi_f(float x) {
    return x > 0.0f ? x + 1.0f : __expf(x);
}

__device__ __forceinline__ void async_copy16(const void* g, void* l) {
    __builtin_amdgcn_global_load_lds(
        (const __attribute__((address_space(1))) uint32_t*)g,
        (__attribute__((address_space(3))) uint32_t*)l, 16, 0, 0);
}

// ---------------------------------------------------------------------------
// fp32 -> bf16 conversion, 8 elems/thread (vectorized streaming)
// ---------------------------------------------------------------------------
__global__ void conv_bf16(const float* __restrict__ src, __bf16* __restrict__ dst) {
    size_t i = ((size_t)blockIdx.x * 256 + threadIdx.x) * 8;
    float4 a = *(const float4*)(src + i);
    float4 b = *(const float4*)(src + i + 4);
    bf16x8 o;
    o[0]=(__bf16)a.x; o[1]=(__bf16)a.y; o[2]=(__bf16)a.z; o[3]=(__bf16)a.w;
    o[4]=(__bf16)b.x; o[5]=(__bf16)b.y; o[6]=(__bf16)b.z; o[7]=(__bf16)b.w;
    *(bf16x8*)(dst + i) = o;
}

__global__ void wconv(const float* __restrict__ src, __bf16* __restrict__ dst) {
    int i = (blockIdx.x * 256 + threadIdx.x) * 4;
    float4 v = *(const float4*)(src + i);
    bf16x4 o;
    o[0] = (__bf16)v.x; o[1] = (__bf16)v.y; o[2] = (__bf16)v.z; o[3] = (__bf16)v.w;
    *(bf16x4*)(dst + i) = o;
}

// ---------------------------------------------------------------------------
// GEMM: Out[m][n] = epi( sum_k A[m][k] * W[n][k] ), both operands bf16 via
// global_load_lds (pre-swizzled source -> XOR-swizzled conflict-free reads).
// EPI: 0 = phi -> bf16 (Q), 1 = phi*mask -> bf16 (K), 2 = mask -> bf16 (V),
//      3 = none -> fp32 (final projection)
// 128x128 tile, BK=64, 256 threads (4 waves 2x2), 16x16x32 bf16 MFMA.
// 1D grid of 2048 blocks, XCD-bijective swizzle: each XCD owns 32 contiguous
// M-panels x all 8 N-columns -> A-panel fetched once per XCD (L2-resident).
// ---------------------------------------------------------------------------
template<int EPI>
__global__ __launch_bounds__(256, 2)
void gemm_bt(const __bf16* __restrict__ A, const __bf16* __restrict__ Wb,
             const float* __restrict__ mask, void* __restrict__ OutV)
{
    const int orig = blockIdx.x;
    const int wgid = (orig & 7) * 256 + (orig >> 3);   // nwg=2048, %8==0: bijective
    const int bm = (wgid >> 3) * 128;
    const int bn = (wgid & 7) * 128;
    const int tid  = threadIdx.x;
    const int lane = tid & 63;
    const int wid  = tid >> 6;
    const int wm = wid >> 1, wn = wid & 1;

    __shared__ __bf16 Al[128 * 64];
    __shared__ __bf16 Bl[128 * 64];

    f32x4 acc[4][4];
    #pragma unroll
    for (int i = 0; i < 4; ++i)
        #pragma unroll
        for (int j = 0; j < 4; ++j) acc[i][j] = (f32x4)0.0f;

    const int sn = wid * 8 + (lane >> 3);
    const int sc = (lane & 7) * 16;

    for (int k0 = 0; k0 < H_; k0 += 64) {
        #pragma unroll
        for (int issue = 0; issue < 4; ++issue) {
            int n = issue * 32 + sn;
            int csw = sc ^ ((n & 7) << 4);
            async_copy16((const char*)(A  + (size_t)(bm + n) * H_ + k0) + csw,
                         (char*)Al + issue * 4096 + wid * 1024);
            async_copy16((const char*)(Wb + (size_t)(bn + n) * H_ + k0) + csw,
                         (char*)Bl + issue * 4096 + wid * 1024);
        }
        __syncthreads();
        #pragma unroll
        for (int ks = 0; ks < 2; ++ks) {
            bf16x8 afr[4], bfr[4];
            #pragma unroll
            for (int mi = 0; mi < 4; ++mi) {
                int r  = wm * 64 + mi * 16 + (lane & 15);
                int cb = (ks * 64 + (lane >> 4) * 16) ^ ((r & 7) << 4);
                afr[mi] = *(const bf16x8*)((const char*)Al + r * 128 + cb);
            }
            #pragma unroll
            for (int ni = 0; ni < 4; ++ni) {
                int r  = wn * 64 + ni * 16 + (lane & 15);
                int cb = (ks * 64 + (lane >> 4) * 16) ^ ((r & 7) << 4);
                bfr[ni] = *(const bf16x8*)((const char*)Bl + r * 128 + cb);
            }
            #pragma unroll
            for (int mi = 0; mi < 4; ++mi)
                #pragma unroll
                for (int ni = 0; ni < 4; ++ni)
                    acc[mi][ni] = __builtin_amdgcn_mfma_f32_16x16x32_bf16(
                        afr[mi], bfr[ni], acc[mi][ni], 0, 0, 0);
        }
        __syncthreads();
    }
    // epilogue: C row = (lane>>4)*4 + j, col = lane&15
    const int gm0 = bm + wm * 64;
    const int gn0 = bn + wn * 64 + (lane & 15);
    #pragma unroll
    for (int mi = 0; mi < 4; ++mi) {
        #pragma unroll
        for (int j = 0; j < 4; ++j) {
            int gm = gm0 + mi * 16 + (lane >> 4) * 4 + j;
            if (EPI == 3) {
                float* op = (float*)OutV + (size_t)gm * H_ + gn0;
                #pragma unroll
                for (int ni = 0; ni < 4; ++ni)
                    op[ni * 16] = acc[mi][ni][j];
            } else {
                float mv = (EPI >= 1) ? mask[gm] : 1.0f;
                __bf16* op = (__bf16*)OutV + (size_t)gm * H_ + gn0;
                #pragma unroll
                for (int ni = 0; ni < 4; ++ni) {
                    float v = acc[mi][ni][j];
                    if (EPI == 0)      v = phi_f(v);
                    else if (EPI == 1) v = phi_f(v) * mv;
                    else               v = v * mv;
                    op[ni * 16] = (__bf16)v;
                }
            }
        }
    }
}

// ---------------------------------------------------------------------------
// KV[bh][dk][dv] += sum_t K[t,dk]*V[t,dv] ; Ksum[bh][dk] += sum_t K[t,dk]
// split-K over t, fp32 atomics into pre-zeroed buffers.
// ---------------------------------------------------------------------------
__global__ __launch_bounds__(256, 4)
void kv_kernel(const __bf16* __restrict__ Kb, const __bf16* __restrict__ Vb,
               float* __restrict__ KV, float* __restrict__ Ksum)
{
    const int bh = blockIdx.y;
    const int b = bh >> 4, h = bh & 15;
    const int tid = threadIdx.x;
    const int dkq = tid >> 4, dvq = tid & 15;
    __shared__ __bf16 Kt[64][72];
    __shared__ __bf16 Vt[64][72];
    float acc[4][4];
    #pragma unroll
    for (int i = 0; i < 4; ++i)
        #pragma unroll
        for (int j = 0; j < 4; ++j) acc[i][j] = 0.0f;
    float ks[4] = {0.0f, 0.0f, 0.0f, 0.0f};

    const int r = tid >> 2, part = tid & 3;
    const size_t base = ((size_t)b * T_ + (size_t)blockIdx.x * 1024) * H_
                        + h * 64 + part * 16;
    for (int it = 0; it < 16; ++it) {
        const size_t rowoff = base + (size_t)(it * 64 + r) * H_;
        *(bf16x8*)&Kt[r][part*16]     = *(const bf16x8*)(Kb + rowoff);
        *(bf16x8*)&Kt[r][part*16 + 8] = *(const bf16x8*)(Kb + rowoff + 8);
        *(bf16x8*)&Vt[r][part*16]     = *(const bf16x8*)(Vb + rowoff);
        *(bf16x8*)&Vt[r][part*16 + 8] = *(const bf16x8*)(Vb + rowoff + 8);
        __syncthreads();
        #pragma unroll 4
        for (int tt = 0; tt < 64; ++tt) {
            bf16x4 k4 = *(const bf16x4*)&Kt[tt][dkq * 4];
            bf16x4 v4 = *(const bf16x4*)&Vt[tt][dvq * 4];
            float kx[4], vx[4];
            #pragma unroll
            for (int i = 0; i < 4; ++i) { kx[i] = (float)k4[i]; vx[i] = (float)v4[i]; }
            #pragma unroll
            for (int i = 0; i < 4; ++i) {
                ks[i] += kx[i];
                #pragma unroll
                for (int j = 0; j < 4; ++j) acc[i][j] += kx[i] * vx[j];
            }
        }
        __syncthreads();
    }
    float* kvp = KV + (size_t)bh * 4096;
    #pragma unroll
    for (int i = 0; i < 4; ++i)
        #pragma unroll
        for (int j = 0; j < 4; ++j)
            atomicAdd(&kvp[(dkq*4 + i) * 64 + dvq*4 + j], acc[i][j]);
    if (dvq == 0) {
        #pragma unroll
        for (int i = 0; i < 4; ++i)
            atomicAdd(&Ksum[bh * 64 + dkq*4 + i], ks[i]);
    }
}

// KV fp32 [bh][dk][dv] -> KVT bf16 [bh][dv][dk]
__global__ void kvt_kernel(const float* __restrict__ KV, __bf16* __restrict__ KVT) {
    int bh = blockIdx.x, tid = threadIdx.x;
    const float* s = KV + (size_t)bh * 4096;
    __bf16* d = KVT + (size_t)bh * 4096;
    for (int i = tid; i < 4096; i += 256) {
        int dk = i >> 6, dv = i & 63;
        d[dv * 64 + dk] = (__bf16)s[i];
    }
}

// ---------------------------------------------------------------------------
// attn: On[b,t,h*64+dv] = (sum_dk Q[t,dk]*KV[dk,dv]) / (Q[t,:].Ksum + 1e-6)
// ---------------------------------------------------------------------------
__global__ __launch_bounds__(256, 2)
void attn_kernel(const __bf16* __restrict__ Qb, const __bf16* __restrict__ KVT,
                 const float* __restrict__ Ksum, __bf16* __restrict__ On)
{
    const int bh = blockIdx.y;
    const int b = bh >> 4, h = bh & 15;
    const int tc = blockIdx.x;
    const int tid = threadIdx.x, lane = tid & 63, wid = tid >> 6;
    __shared__ __bf16 kvl[64][72];
    __shared__ float dinv[256];

    {
        const int r = tid >> 2, part = tid & 3;
        const __bf16* src = KVT + (size_t)bh * 4096 + r * 64 + part * 16;
        *(bf16x8*)&kvl[r][part*16]     = *(const bf16x8*)src;
        *(bf16x8*)&kvl[r][part*16 + 8] = *(const bf16x8*)(src + 8);
    }
    {
        const int t = tc * 256 + tid;
        const __bf16* qp = Qb + ((size_t)b * T_ + t) * H_ + h * 64;
        const float* kp = Ksum + bh * 64;
        float s = 0.0f;
        #pragma unroll
        for (int i = 0; i < 8; ++i) {
            bf16x8 qv = *(const bf16x8*)(qp + i * 8);
            #pragma unroll
            for (int j = 0; j < 8; ++j) s += (float)qv[j] * kp[i*8 + j];
        }
        dinv[tid] = 1.0f / (s + 1e-6f);
    }
    __syncthreads();

    f32x4 acc[4][4];
    #pragma unroll
    for (int i = 0; i < 4; ++i)
        #pragma unroll
        for (int j = 0; j < 4; ++j) acc[i][j] = (f32x4)0.0f;

    const int t0 = tc * 256 + wid * 64;
    #pragma unroll
    for (int ks = 0; ks < 2; ++ks) {
        bf16x8 afr[4], bfr[4];
        #pragma unroll
        for (int mi = 0; mi < 4; ++mi) {
            int t = t0 + mi * 16 + (lane & 15);
            afr[mi] = *(const bf16x8*)(Qb + ((size_t)b * T_ + t) * H_ + h * 64
                                       + ks * 32 + (lane >> 4) * 8);
        }
        #pragma unroll
        for (int ni = 0; ni < 4; ++ni) {
            int dv = ni * 16 + (lane & 15);
            bfr[ni] = *(const bf16x8*)&kvl[dv][ks * 32 + (lane >> 4) * 8];
        }
        #pragma unroll
        for (int mi = 0; mi < 4; ++mi)
            #pragma unroll
            for (int ni = 0; ni < 4; ++ni)
                acc[mi][ni] = __builtin_amdgcn_mfma_f32_16x16x32_bf16(
                    afr[mi], bfr[ni], acc[mi][ni], 0, 0, 0);
    }
    #pragma unroll
    for (int mi = 0; mi < 4; ++mi)
        #pragma unroll
        for (int j = 0; j < 4; ++j) {
            int lt = wid * 64 + mi * 16 + (lane >> 4) * 4 + j;
            float z = dinv[lt];
            int t = tc * 256 + lt;
            __bf16* op = On + ((size_t)b * T_ + t) * H_ + h * 64 + (lane & 15);
            #pragma unroll
            for (int ni = 0; ni < 4; ++ni)
                op[ni * 16] = (__bf16)(acc[mi][ni][j] * z);
        }
}

// ---------------------------------------------------------------------------
extern "C" void kernel_launch(void* const* d_in, const int* in_sizes, int n_in,
                              void* d_out, int out_size, void* d_ws, size_t ws_size,
                              hipStream_t stream) {
    (void)in_sizes; (void)n_in; (void)out_size; (void)ws_size;
    const float* q    = (const float*)d_in[0];
    const float* k    = (const float*)d_in[1];
    const float* v    = (const float*)d_in[2];
    const float* mask = (const float*)d_in[3];
    const float* Wq   = (const float*)d_in[4];
    const float* Wk   = (const float*)d_in[5];
    const float* Wv   = (const float*)d_in[6];
    const float* Wo   = (const float*)d_in[7];
    float* out = (float*)d_out;

    char* ws = (char*)d_ws;
    const size_t WELEM = (size_t)H_ * H_;      // 1 Mi elems
    const size_t PELEM = (size_t)BT_ * H_;     // 32 Mi elems
    __bf16* Wqb = (__bf16*)ws;
    __bf16* Wkb = Wqb + WELEM;
    __bf16* Wvb = Wkb + WELEM;
    __bf16* Wob = Wvb + WELEM;
    __bf16* Qb  = Wob + WELEM;
    __bf16* Kb  = Qb + PELEM;
    __bf16* Vb  = Kb + PELEM;
    __bf16* tmp = Vb + PELEM;                 // conv buffer, later An
    float*  KV  = (float*)(tmp + PELEM);
    float*  Ks  = KV + (size_t)B_ * NH_ * D_ * D_;
    __bf16* KVT = (__bf16*)(Ks + (size_t)B_ * NH_ * D_);
    // total ws use: ~266 MB

    hipMemsetAsync(KV, 0, ((size_t)B_*NH_*D_*D_ + (size_t)B_*NH_*D_) * sizeof(float), stream);

    wconv<<<1024, 256, 0, stream>>>(Wq, Wqb);
    wconv<<<1024, 256, 0, stream>>>(Wk, Wkb);
    wconv<<<1024, 256, 0, stream>>>(Wv, Wvb);
    wconv<<<1024, 256, 0, stream>>>(Wo, Wob);

    const int cgrid = (int)(PELEM / (256 * 8));   // 16384
    conv_bf16<<<cgrid, 256, 0, stream>>>(q, tmp);
    gemm_bt<0><<<2048, 256, 0, stream>>>(tmp, Wqb, mask, Qb);
    conv_bf16<<<cgrid, 256, 0, stream>>>(k, tmp);
    gemm_bt<1><<<2048, 256, 0, stream>>>(tmp, Wkb, mask, Kb);
    conv_bf16<<<cgrid, 256, 0, stream>>>(v, tmp);
    gemm_bt<2><<<2048, 256, 0, stream>>>(tmp, Wvb, mask, Vb);

    kv_kernel<<<dim3(T_/1024, B_*NH_), 256, 0, stream>>>(Kb, Vb, KV, Ks);
    kvt_kernel<<<B_*NH_, 256, 0, stream>>>(KV, KVT);
    attn_kernel<<<dim3(T_/256, B_*NH_), 256, 0, stream>>>(Qb, KVT, Ks, tmp);
    gemm_bt<3><<<2048, 256, 0, stream>>>(tmp, Wob, mask, out);
}

// Round 3
// 472.943 us; speedup vs baseline: 1.7058x; 1.1811x over previous
//
#include <hip/hip_runtime.h>
#include <hip/hip_bf16.h>
#include <stdint.h>

#define B_  4
#define T_  8192
#define H_  1024
#define NH_ 16
#define D_  64
#define BT_ (B_*T_)

typedef __attribute__((ext_vector_type(8))) __bf16 bf16x8;
typedef __attribute__((ext_vector_type(4))) __bf16 bf16x4;
typedef __attribute__((ext_vector_type(4))) float  f32x4;

__device__ __forceinline__ float phi_f(float x) {
    return x > 0.0f ? x + 1.0f : __expf(x);
}

__device__ __forceinline__ void async_copy16(const void* g, void* l) {
    __builtin_amdgcn_global_load_lds(
        (const __attribute__((address_space(1))) uint32_t*)g,
        (__attribute__((address_space(3))) uint32_t*)l, 16, 0, 0);
}

// ---------------------------------------------------------------------------
// fp32 -> bf16 conversion, 8 elems/thread (vectorized streaming)
// ---------------------------------------------------------------------------
__global__ void conv_bf16(const float* __restrict__ src, __bf16* __restrict__ dst) {
    size_t i = ((size_t)blockIdx.x * 256 + threadIdx.x) * 8;
    float4 a = *(const float4*)(src + i);
    float4 b = *(const float4*)(src + i + 4);
    bf16x8 o;
    o[0]=(__bf16)a.x; o[1]=(__bf16)a.y; o[2]=(__bf16)a.z; o[3]=(__bf16)a.w;
    o[4]=(__bf16)b.x; o[5]=(__bf16)b.y; o[6]=(__bf16)b.z; o[7]=(__bf16)b.w;
    *(bf16x8*)(dst + i) = o;
}

__global__ void wconv(const float* __restrict__ src, __bf16* __restrict__ dst) {
    int i = (blockIdx.x * 256 + threadIdx.x) * 4;
    float4 v = *(const float4*)(src + i);
    bf16x4 o;
    o[0] = (__bf16)v.x; o[1] = (__bf16)v.y; o[2] = (__bf16)v.z; o[3] = (__bf16)v.w;
    *(bf16x4*)(dst + i) = o;
}

// ---------------------------------------------------------------------------
// GEMM: Out[m][n] = epi( sum_k A[m][k] * W[n][k] ), both operands bf16 via
// global_load_lds (pre-swizzled source -> XOR-swizzled conflict-free reads).
// EPI: 0 = phi -> bf16 (Q), 1 = phi*mask -> bf16 (K), 2 = mask -> bf16 (V),
//      3 = none -> fp32 (final projection)
// ---------------------------------------------------------------------------
template<int EPI>
__global__ __launch_bounds__(256, 2)
void gemm_bt(const __bf16* __restrict__ A, const __bf16* __restrict__ Wb,
             const float* __restrict__ mask, void* __restrict__ OutV)
{
    const int orig = blockIdx.x;
    const int wgid = (orig & 7) * 256 + (orig >> 3);   // nwg=2048, %8==0: bijective
    const int bm = (wgid >> 3) * 128;
    const int bn = (wgid & 7) * 128;
    const int tid  = threadIdx.x;
    const int lane = tid & 63;
    const int wid  = tid >> 6;
    const int wm = wid >> 1, wn = wid & 1;

    __shared__ __bf16 Al[128 * 64];
    __shared__ __bf16 Bl[128 * 64];

    f32x4 acc[4][4];
    #pragma unroll
    for (int i = 0; i < 4; ++i)
        #pragma unroll
        for (int j = 0; j < 4; ++j) acc[i][j] = (f32x4)0.0f;

    const int sn = wid * 8 + (lane >> 3);
    const int sc = (lane & 7) * 16;

    for (int k0 = 0; k0 < H_; k0 += 64) {
        #pragma unroll
        for (int issue = 0; issue < 4; ++issue) {
            int n = issue * 32 + sn;
            int csw = sc ^ ((n & 7) << 4);
            async_copy16((const char*)(A  + (size_t)(bm + n) * H_ + k0) + csw,
                         (char*)Al + issue * 4096 + wid * 1024);
            async_copy16((const char*)(Wb + (size_t)(bn + n) * H_ + k0) + csw,
                         (char*)Bl + issue * 4096 + wid * 1024);
        }
        __syncthreads();
        #pragma unroll
        for (int ks = 0; ks < 2; ++ks) {
            bf16x8 afr[4], bfr[4];
            #pragma unroll
            for (int mi = 0; mi < 4; ++mi) {
                int r  = wm * 64 + mi * 16 + (lane & 15);
                int cb = (ks * 64 + (lane >> 4) * 16) ^ ((r & 7) << 4);
                afr[mi] = *(const bf16x8*)((const char*)Al + r * 128 + cb);
            }
            #pragma unroll
            for (int ni = 0; ni < 4; ++ni) {
                int r  = wn * 64 + ni * 16 + (lane & 15);
                int cb = (ks * 64 + (lane >> 4) * 16) ^ ((r & 7) << 4);
                bfr[ni] = *(const bf16x8*)((const char*)Bl + r * 128 + cb);
            }
            #pragma unroll
            for (int mi = 0; mi < 4; ++mi)
                #pragma unroll
                for (int ni = 0; ni < 4; ++ni)
                    acc[mi][ni] = __builtin_amdgcn_mfma_f32_16x16x32_bf16(
                        afr[mi], bfr[ni], acc[mi][ni], 0, 0, 0);
        }
        __syncthreads();
    }
    const int gm0 = bm + wm * 64;
    const int gn0 = bn + wn * 64 + (lane & 15);
    #pragma unroll
    for (int mi = 0; mi < 4; ++mi) {
        #pragma unroll
        for (int j = 0; j < 4; ++j) {
            int gm = gm0 + mi * 16 + (lane >> 4) * 4 + j;
            if (EPI == 3) {
                float* op = (float*)OutV + (size_t)gm * H_ + gn0;
                #pragma unroll
                for (int ni = 0; ni < 4; ++ni)
                    op[ni * 16] = acc[mi][ni][j];
            } else {
                float mv = (EPI >= 1) ? mask[gm] : 1.0f;
                __bf16* op = (__bf16*)OutV + (size_t)gm * H_ + gn0;
                #pragma unroll
                for (int ni = 0; ni < 4; ++ni) {
                    float v = acc[mi][ni][j];
                    if (EPI == 0)      v = phi_f(v);
                    else if (EPI == 1) v = phi_f(v) * mv;
                    else               v = v * mv;
                    op[ni * 16] = (__bf16)v;
                }
            }
        }
    }
}

// ---------------------------------------------------------------------------
// KV[bh][dk][dv] += sum_t K[t,dk]*V[t,dv] via MFMA; Ksum[bh][dk] += sum_t K[t,dk].
// Per block: one (b,h), 1024-t chunk, 16 tiles of 64 t. Tiles are transposed
// into LDS at staging (scalar b16 writes, 144B row stride + XOR swizzle
// ((dk>>3)&7)<<4 on both write and read -> frag ds_read_b128 conflict-free,
// writes ~2-way). Wave w owns dk strip w*16..w*16+15, all 64 dv.
// fp32 atomics into pre-zeroed KV/Ksum.
// ---------------------------------------------------------------------------
__global__ __launch_bounds__(256, 2)
void kv_kernel(const __bf16* __restrict__ Kb, const __bf16* __restrict__ Vb,
               float* __restrict__ KV, float* __restrict__ Ksum)
{
    const int bh = blockIdx.y;
    const int b = bh >> 4, h = bh & 15;
    const int tid = threadIdx.x, lane = tid & 63, wid = tid >> 6;

    __shared__ char KtRaw[64 * 144];   // [dk][t] bf16, 72-elem stride, swizzled
    __shared__ char VtRaw[64 * 144];   // [dv][t] bf16
    __shared__ float ksl[64];

    const int st  = tid >> 3;          // t within tile: st and st+32
    const int dkg = tid & 7;
    const int dk0 = dkg * 8;
    const int swzT = (dkg & 7) << 4;   // (dk>>3)&7 == dkg for dk = dk0+j, j<8

    if (tid < 64) ksl[tid] = 0.0f;

    f32x4 acc[4];
    #pragma unroll
    for (int i = 0; i < 4; ++i) acc[i] = (f32x4)0.0f;
    float ksacc[8];
    #pragma unroll
    for (int i = 0; i < 8; ++i) ksacc[i] = 0.0f;

    const size_t gbase = ((size_t)b * T_ + (size_t)blockIdx.x * 1024) * H_
                         + h * 64 + dk0;

    bf16x8 ka, kc, va, vc;
    {   // prefetch tile 0
        const __bf16* p  = Kb + gbase;
        const __bf16* pv = Vb + gbase;
        ka = *(const bf16x8*)(p  + (size_t)st * H_);
        kc = *(const bf16x8*)(p  + (size_t)(st + 32) * H_);
        va = *(const bf16x8*)(pv + (size_t)st * H_);
        vc = *(const bf16x8*)(pv + (size_t)(st + 32) * H_);
    }

    for (int tile = 0; tile < 16; ++tile) {
        __syncthreads();   // previous MFMA phase done; LDS free
        // transposed scalar writes: Kt[dk0+j][st], Kt[dk0+j][st+32], same V
        #pragma unroll
        for (int j = 0; j < 8; ++j) {
            int rowb = (dk0 + j) * 144;
            *(__bf16*)(KtRaw + ((rowb + 2*st)        ^ swzT)) = ka[j];
            *(__bf16*)(KtRaw + ((rowb + 2*(st + 32)) ^ swzT)) = kc[j];
            *(__bf16*)(VtRaw + ((rowb + 2*st)        ^ swzT)) = va[j];
            *(__bf16*)(VtRaw + ((rowb + 2*(st + 32)) ^ swzT)) = vc[j];
            ksacc[j] += (float)ka[j] + (float)kc[j];
        }
        // prefetch next tile (global latency hides under MFMA phase)
        if (tile < 15) {
            const __bf16* p  = Kb + gbase + (size_t)(tile + 1) * 64 * H_;
            const __bf16* pv = Vb + gbase + (size_t)(tile + 1) * 64 * H_;
            ka = *(const bf16x8*)(p  + (size_t)st * H_);
            kc = *(const bf16x8*)(p  + (size_t)(st + 32) * H_);
            va = *(const bf16x8*)(pv + (size_t)st * H_);
            vc = *(const bf16x8*)(pv + (size_t)(st + 32) * H_);
        }
        __syncthreads();   // tile staged
        #pragma unroll
        for (int ks = 0; ks < 2; ++ks) {
            int r = wid * 16 + (lane & 15);
            int cb = (r * 144 + (ks * 64 + (lane >> 4) * 16)) ^ (((r >> 3) & 7) << 4);
            bf16x8 af = *(const bf16x8*)(KtRaw + cb);
            #pragma unroll
            for (int ni = 0; ni < 4; ++ni) {
                int rv = ni * 16 + (lane & 15);
                int cv = (rv * 144 + (ks * 64 + (lane >> 4) * 16)) ^ (((rv >> 3) & 7) << 4);
                bf16x8 bf = *(const bf16x8*)(VtRaw + cv);
                acc[ni] = __builtin_amdgcn_mfma_f32_16x16x32_bf16(af, bf, acc[ni], 0, 0, 0);
            }
        }
    }

    // KV atomics: C row = wid*16 + (lane>>4)*4 + jj (dk), col = ni*16 + (lane&15) (dv)
    float* kvp = KV + (size_t)bh * 4096;
    #pragma unroll
    for (int ni = 0; ni < 4; ++ni)
        #pragma unroll
        for (int jj = 0; jj < 4; ++jj) {
            int dk = wid * 16 + (lane >> 4) * 4 + jj;
            int dv = ni * 16 + (lane & 15);
            atomicAdd(&kvp[dk * 64 + dv], acc[ni][jj]);
        }

    // Ksum reduction: reg -> LDS atomics -> one global atomic per dk
    __syncthreads();
    #pragma unroll
    for (int j = 0; j < 8; ++j)
        atomicAdd(&ksl[dk0 + j], ksacc[j]);
    __syncthreads();
    if (tid < 64)
        atomicAdd(&Ksum[bh * 64 + tid], ksl[tid]);
}

// KV fp32 [bh][dk][dv] -> KVT bf16 [bh][dv][dk]
__global__ void kvt_kernel(const float* __restrict__ KV, __bf16* __restrict__ KVT) {
    int bh = blockIdx.x, tid = threadIdx.x;
    const float* s = KV + (size_t)bh * 4096;
    __bf16* d = KVT + (size_t)bh * 4096;
    for (int i = tid; i < 4096; i += 256) {
        int dk = i >> 6, dv = i & 63;
        d[dv * 64 + dk] = (__bf16)s[i];
    }
}

// ---------------------------------------------------------------------------
// attn: On[b,t,h*64+dv] = (sum_dk Q[t,dk]*KV[dk,dv]) / (Q[t,:].Ksum + 1e-6)
// ---------------------------------------------------------------------------
__global__ __launch_bounds__(256, 2)
void attn_kernel(const __bf16* __restrict__ Qb, const __bf16* __restrict__ KVT,
                 const float* __restrict__ Ksum, __bf16* __restrict__ On)
{
    const int bh = blockIdx.y;
    const int b = bh >> 4, h = bh & 15;
    const int tc = blockIdx.x;
    const int tid = threadIdx.x, lane = tid & 63, wid = tid >> 6;
    __shared__ __bf16 kvl[64][72];
    __shared__ float dinv[256];

    {
        const int r = tid >> 2, part = tid & 3;
        const __bf16* src = KVT + (size_t)bh * 4096 + r * 64 + part * 16;
        *(bf16x8*)&kvl[r][part*16]     = *(const bf16x8*)src;
        *(bf16x8*)&kvl[r][part*16 + 8] = *(const bf16x8*)(src + 8);
    }
    {
        const int t = tc * 256 + tid;
        const __bf16* qp = Qb + ((size_t)b * T_ + t) * H_ + h * 64;
        const float* kp = Ksum + bh * 64;
        float s = 0.0f;
        #pragma unroll
        for (int i = 0; i < 8; ++i) {
            bf16x8 qv = *(const bf16x8*)(qp + i * 8);
            #pragma unroll
            for (int j = 0; j < 8; ++j) s += (float)qv[j] * kp[i*8 + j];
        }
        dinv[tid] = 1.0f / (s + 1e-6f);
    }
    __syncthreads();

    f32x4 acc[4][4];
    #pragma unroll
    for (int i = 0; i < 4; ++i)
        #pragma unroll
        for (int j = 0; j < 4; ++j) acc[i][j] = (f32x4)0.0f;

    const int t0 = tc * 256 + wid * 64;
    #pragma unroll
    for (int ks = 0; ks < 2; ++ks) {
        bf16x8 afr[4], bfr[4];
        #pragma unroll
        for (int mi = 0; mi < 4; ++mi) {
            int t = t0 + mi * 16 + (lane & 15);
            afr[mi] = *(const bf16x8*)(Qb + ((size_t)b * T_ + t) * H_ + h * 64
                                       + ks * 32 + (lane >> 4) * 8);
        }
        #pragma unroll
        for (int ni = 0; ni < 4; ++ni) {
            int dv = ni * 16 + (lane & 15);
            bfr[ni] = *(const bf16x8*)&kvl[dv][ks * 32 + (lane >> 4) * 8];
        }
        #pragma unroll
        for (int mi = 0; mi < 4; ++mi)
            #pragma unroll
            for (int ni = 0; ni < 4; ++ni)
                acc[mi][ni] = __builtin_amdgcn_mfma_f32_16x16x32_bf16(
                    afr[mi], bfr[ni], acc[mi][ni], 0, 0, 0);
    }
    #pragma unroll
    for (int mi = 0; mi < 4; ++mi)
        #pragma unroll
        for (int j = 0; j < 4; ++j) {
            int lt = wid * 64 + mi * 16 + (lane >> 4) * 4 + j;
            float z = dinv[lt];
            int t = tc * 256 + lt;
            __bf16* op = On + ((size_t)b * T_ + t) * H_ + h * 64 + (lane & 15);
            #pragma unroll
            for (int ni = 0; ni < 4; ++ni)
                op[ni * 16] = (__bf16)(acc[mi][ni][j] * z);
        }
}

// ---------------------------------------------------------------------------
extern "C" void kernel_launch(void* const* d_in, const int* in_sizes, int n_in,
                              void* d_out, int out_size, void* d_ws, size_t ws_size,
                              hipStream_t stream) {
    (void)in_sizes; (void)n_in; (void)out_size; (void)ws_size;
    const float* q    = (const float*)d_in[0];
    const float* k    = (const float*)d_in[1];
    const float* v    = (const float*)d_in[2];
    const float* mask = (const float*)d_in[3];
    const float* Wq   = (const float*)d_in[4];
    const float* Wk   = (const float*)d_in[5];
    const float* Wv   = (const float*)d_in[6];
    const float* Wo   = (const float*)d_in[7];
    float* out = (float*)d_out;

    char* ws = (char*)d_ws;
    const size_t WELEM = (size_t)H_ * H_;      // 1 Mi elems
    const size_t PELEM = (size_t)BT_ * H_;     // 32 Mi elems
    __bf16* Wqb = (__bf16*)ws;
    __bf16* Wkb = Wqb + WELEM;
    __bf16* Wvb = Wkb + WELEM;
    __bf16* Wob = Wvb + WELEM;
    __bf16* Qb  = Wob + WELEM;
    __bf16* Kb  = Qb + PELEM;
    __bf16* Vb  = Kb + PELEM;
    __bf16* tmp = Vb + PELEM;                 // conv buffer, later attn out
    float*  KV  = (float*)(tmp + PELEM);
    float*  Ks  = KV + (size_t)B_ * NH_ * D_ * D_;
    __bf16* KVT = (__bf16*)(Ks + (size_t)B_ * NH_ * D_);

    hipMemsetAsync(KV, 0, ((size_t)B_*NH_*D_*D_ + (size_t)B_*NH_*D_) * sizeof(float), stream);

    wconv<<<1024, 256, 0, stream>>>(Wq, Wqb);
    wconv<<<1024, 256, 0, stream>>>(Wk, Wkb);
    wconv<<<1024, 256, 0, stream>>>(Wv, Wvb);
    wconv<<<1024, 256, 0, stream>>>(Wo, Wob);

    const int cgrid = (int)(PELEM / (256 * 8));   // 16384
    conv_bf16<<<cgrid, 256, 0, stream>>>(q, tmp);
    gemm_bt<0><<<2048, 256, 0, stream>>>(tmp, Wqb, mask, Qb);
    conv_bf16<<<cgrid, 256, 0, stream>>>(k, tmp);
    gemm_bt<1><<<2048, 256, 0, stream>>>(tmp, Wkb, mask, Kb);
    conv_bf16<<<cgrid, 256, 0, stream>>>(v, tmp);
    gemm_bt<2><<<2048, 256, 0, stream>>>(tmp, Wvb, mask, Vb);

    kv_kernel<<<dim3(T_/1024, B_*NH_), 256, 0, stream>>>(Kb, Vb, KV, Ks);
    kvt_kernel<<<B_*NH_, 256, 0, stream>>>(KV, KVT);
    attn_kernel<<<dim3(T_/256, B_*NH_), 256, 0, stream>>>(Qb, KVT, Ks, tmp);
    gemm_bt<3><<<2048, 256, 0, stream>>>(tmp, Wob, mask, out);
}

// Round 4
// 460.656 us; speedup vs baseline: 1.7513x; 1.0267x over previous
//
#include <hip/hip_runtime.h>
#include <hip/hip_bf16.h>
#include <stdint.h>

#define B_  4
#define T_  8192
#define H_  1024
#define NH_ 16
#define D_  64
#define BT_ (B_*T_)

typedef __attribute__((ext_vector_type(8))) __bf16 bf16x8;
typedef __attribute__((ext_vector_type(4))) __bf16 bf16x4;
typedef __attribute__((ext_vector_type(4))) float  f32x4;

__device__ __forceinline__ float phi_f(float x) {
    return x > 0.0f ? x + 1.0f : __expf(x);
}

__device__ __forceinline__ void async_copy16(const void* g, void* l) {
    __builtin_amdgcn_global_load_lds(
        (const __attribute__((address_space(1))) uint32_t*)g,
        (__attribute__((address_space(3))) uint32_t*)l, 16, 0, 0);
}

// ---------------------------------------------------------------------------
// fp32 -> bf16 conversion, 8 elems/thread (vectorized streaming)
// ---------------------------------------------------------------------------
__global__ void conv_bf16(const float* __restrict__ src, __bf16* __restrict__ dst) {
    size_t i = ((size_t)blockIdx.x * 256 + threadIdx.x) * 8;
    float4 a = *(const float4*)(src + i);
    float4 b = *(const float4*)(src + i + 4);
    bf16x8 o;
    o[0]=(__bf16)a.x; o[1]=(__bf16)a.y; o[2]=(__bf16)a.z; o[3]=(__bf16)a.w;
    o[4]=(__bf16)b.x; o[5]=(__bf16)b.y; o[6]=(__bf16)b.z; o[7]=(__bf16)b.w;
    *(bf16x8*)(dst + i) = o;
}

// all four weight matrices in one launch; blockIdx.y selects
__global__ void wconv4(const float* __restrict__ s0, const float* __restrict__ s1,
                       const float* __restrict__ s2, const float* __restrict__ s3,
                       __bf16* __restrict__ d0, __bf16* __restrict__ d1,
                       __bf16* __restrict__ d2, __bf16* __restrict__ d3) {
    const float* s; __bf16* d;
    switch (blockIdx.y) {
        case 0: s = s0; d = d0; break;
        case 1: s = s1; d = d1; break;
        case 2: s = s2; d = d2; break;
        default: s = s3; d = d3; break;
    }
    int i = (blockIdx.x * 256 + threadIdx.x) * 4;
    float4 v = *(const float4*)(s + i);
    bf16x4 o;
    o[0] = (__bf16)v.x; o[1] = (__bf16)v.y; o[2] = (__bf16)v.z; o[3] = (__bf16)v.w;
    *(bf16x4*)(d + i) = o;
}

// ---------------------------------------------------------------------------
// GEMM: Out[m][n] = epi( sum_k A[m][k] * W[n][k] ), both operands bf16 via
// global_load_lds (pre-swizzled source -> XOR-swizzled conflict-free reads).
// EPI: 0 = phi -> bf16 (Q), 1 = phi*mask -> bf16 (K), 2 = mask -> bf16 (V),
//      3 = none -> fp32 (final projection)
// ---------------------------------------------------------------------------
template<int EPI>
__global__ __launch_bounds__(256, 2)
void gemm_bt(const __bf16* __restrict__ A, const __bf16* __restrict__ Wb,
             const float* __restrict__ mask, void* __restrict__ OutV)
{
    const int orig = blockIdx.x;
    const int wgid = (orig & 7) * 256 + (orig >> 3);   // nwg=2048, %8==0: bijective
    const int bm = (wgid >> 3) * 128;
    const int bn = (wgid & 7) * 128;
    const int tid  = threadIdx.x;
    const int lane = tid & 63;
    const int wid  = tid >> 6;
    const int wm = wid >> 1, wn = wid & 1;

    __shared__ __bf16 Al[128 * 64];
    __shared__ __bf16 Bl[128 * 64];

    f32x4 acc[4][4];
    #pragma unroll
    for (int i = 0; i < 4; ++i)
        #pragma unroll
        for (int j = 0; j < 4; ++j) acc[i][j] = (f32x4)0.0f;

    const int sn = wid * 8 + (lane >> 3);
    const int sc = (lane & 7) * 16;

    for (int k0 = 0; k0 < H_; k0 += 64) {
        #pragma unroll
        for (int issue = 0; issue < 4; ++issue) {
            int n = issue * 32 + sn;
            int csw = sc ^ ((n & 7) << 4);
            async_copy16((const char*)(A  + (size_t)(bm + n) * H_ + k0) + csw,
                         (char*)Al + issue * 4096 + wid * 1024);
            async_copy16((const char*)(Wb + (size_t)(bn + n) * H_ + k0) + csw,
                         (char*)Bl + issue * 4096 + wid * 1024);
        }
        __syncthreads();
        #pragma unroll
        for (int ks = 0; ks < 2; ++ks) {
            bf16x8 afr[4], bfr[4];
            #pragma unroll
            for (int mi = 0; mi < 4; ++mi) {
                int r  = wm * 64 + mi * 16 + (lane & 15);
                int cb = (ks * 64 + (lane >> 4) * 16) ^ ((r & 7) << 4);
                afr[mi] = *(const bf16x8*)((const char*)Al + r * 128 + cb);
            }
            #pragma unroll
            for (int ni = 0; ni < 4; ++ni) {
                int r  = wn * 64 + ni * 16 + (lane & 15);
                int cb = (ks * 64 + (lane >> 4) * 16) ^ ((r & 7) << 4);
                bfr[ni] = *(const bf16x8*)((const char*)Bl + r * 128 + cb);
            }
            #pragma unroll
            for (int mi = 0; mi < 4; ++mi)
                #pragma unroll
                for (int ni = 0; ni < 4; ++ni)
                    acc[mi][ni] = __builtin_amdgcn_mfma_f32_16x16x32_bf16(
                        afr[mi], bfr[ni], acc[mi][ni], 0, 0, 0);
        }
        __syncthreads();
    }
    const int gm0 = bm + wm * 64;
    const int gn0 = bn + wn * 64 + (lane & 15);
    #pragma unroll
    for (int mi = 0; mi < 4; ++mi) {
        #pragma unroll
        for (int j = 0; j < 4; ++j) {
            int gm = gm0 + mi * 16 + (lane >> 4) * 4 + j;
            if (EPI == 3) {
                float* op = (float*)OutV + (size_t)gm * H_ + gn0;
                #pragma unroll
                for (int ni = 0; ni < 4; ++ni)
                    op[ni * 16] = acc[mi][ni][j];
            } else {
                float mv = (EPI >= 1) ? mask[gm] : 1.0f;
                __bf16* op = (__bf16*)OutV + (size_t)gm * H_ + gn0;
                #pragma unroll
                for (int ni = 0; ni < 4; ++ni) {
                    float v = acc[mi][ni][j];
                    if (EPI == 0)      v = phi_f(v);
                    else if (EPI == 1) v = phi_f(v) * mv;
                    else               v = v * mv;
                    op[ni * 16] = (__bf16)v;
                }
            }
        }
    }
}

// ---------------------------------------------------------------------------
// KV partials via MFMA: KVp[chunk][bh][dk][dv] = sum_{t in chunk} K[t,dk]*V[t,dv]
// Ksp[chunk][bh][dk] = sum_{t in chunk} K[t,dk].  Non-atomic, no init needed.
// Tiles transposed into LDS at staging (scalar b16 writes, 144B row stride +
// XOR swizzle on write and read -> frag ds_read_b128 conflict-free).
// ---------------------------------------------------------------------------
__global__ __launch_bounds__(256, 2)
void kv_kernel(const __bf16* __restrict__ Kb, const __bf16* __restrict__ Vb,
               float* __restrict__ KVp, float* __restrict__ Ksp)
{
    const int chunk = blockIdx.x;
    const int bh = blockIdx.y;
    const int b = bh >> 4, h = bh & 15;
    const int tid = threadIdx.x, lane = tid & 63, wid = tid >> 6;

    __shared__ char KtRaw[64 * 144];   // [dk][t] bf16, 72-elem stride, swizzled
    __shared__ char VtRaw[64 * 144];   // [dv][t] bf16
    __shared__ float ksbuf[32][64];    // deterministic Ksum reduce

    const int st  = tid >> 3;          // t within tile: st and st+32
    const int dkg = tid & 7;
    const int dk0 = dkg * 8;
    const int swzT = (dkg & 7) << 4;

    f32x4 acc[4];
    #pragma unroll
    for (int i = 0; i < 4; ++i) acc[i] = (f32x4)0.0f;
    float ksacc[8];
    #pragma unroll
    for (int i = 0; i < 8; ++i) ksacc[i] = 0.0f;

    const size_t gbase = ((size_t)b * T_ + (size_t)chunk * 1024) * H_
                         + h * 64 + dk0;

    bf16x8 ka, kc, va, vc;
    {   // prefetch tile 0
        const __bf16* p  = Kb + gbase;
        const __bf16* pv = Vb + gbase;
        ka = *(const bf16x8*)(p  + (size_t)st * H_);
        kc = *(const bf16x8*)(p  + (size_t)(st + 32) * H_);
        va = *(const bf16x8*)(pv + (size_t)st * H_);
        vc = *(const bf16x8*)(pv + (size_t)(st + 32) * H_);
    }

    for (int tile = 0; tile < 16; ++tile) {
        __syncthreads();
        #pragma unroll
        for (int j = 0; j < 8; ++j) {
            int rowb = (dk0 + j) * 144;
            *(__bf16*)(KtRaw + ((rowb + 2*st)        ^ swzT)) = ka[j];
            *(__bf16*)(KtRaw + ((rowb + 2*(st + 32)) ^ swzT)) = kc[j];
            *(__bf16*)(VtRaw + ((rowb + 2*st)        ^ swzT)) = va[j];
            *(__bf16*)(VtRaw + ((rowb + 2*(st + 32)) ^ swzT)) = vc[j];
            ksacc[j] += (float)ka[j] + (float)kc[j];
        }
        if (tile < 15) {
            const __bf16* p  = Kb + gbase + (size_t)(tile + 1) * 64 * H_;
            const __bf16* pv = Vb + gbase + (size_t)(tile + 1) * 64 * H_;
            ka = *(const bf16x8*)(p  + (size_t)st * H_);
            kc = *(const bf16x8*)(p  + (size_t)(st + 32) * H_);
            va = *(const bf16x8*)(pv + (size_t)st * H_);
            vc = *(const bf16x8*)(pv + (size_t)(st + 32) * H_);
        }
        __syncthreads();
        #pragma unroll
        for (int ks = 0; ks < 2; ++ks) {
            int r = wid * 16 + (lane & 15);
            int cb = (r * 144 + (ks * 64 + (lane >> 4) * 16)) ^ (((r >> 3) & 7) << 4);
            bf16x8 af = *(const bf16x8*)(KtRaw + cb);
            #pragma unroll
            for (int ni = 0; ni < 4; ++ni) {
                int rv = ni * 16 + (lane & 15);
                int cv = (rv * 144 + (ks * 64 + (lane >> 4) * 16)) ^ (((rv >> 3) & 7) << 4);
                bf16x8 bf = *(const bf16x8*)(VtRaw + cv);
                acc[ni] = __builtin_amdgcn_mfma_f32_16x16x32_bf16(af, bf, acc[ni], 0, 0, 0);
            }
        }
    }

    // non-atomic partial store: C row dk = wid*16+(lane>>4)*4+jj, col dv = ni*16+(lane&15)
    float* kvp = KVp + ((size_t)chunk * 64 + bh) * 4096;
    #pragma unroll
    for (int ni = 0; ni < 4; ++ni)
        #pragma unroll
        for (int jj = 0; jj < 4; ++jj) {
            int dk = wid * 16 + (lane >> 4) * 4 + jj;
            int dv = ni * 16 + (lane & 15);
            kvp[dk * 64 + dv] = acc[ni][jj];
        }

    // deterministic Ksum partial: ksbuf[st][dk] then 64-thread column sums
    #pragma unroll
    for (int j = 0; j < 8; ++j)
        ksbuf[st][dk0 + j] = ksacc[j];
    __syncthreads();
    if (tid < 64) {
        float s = 0.0f;
        #pragma unroll 8
        for (int st2 = 0; st2 < 32; ++st2) s += ksbuf[st2][tid];
        Ksp[((size_t)chunk * 64 + bh) * 64 + tid] = s;
    }
}

// sum 8 chunk-partials: KVT bf16 [bh][dv][dk] (transposed), Ks fp32 [bh][dk]
__global__ void kvt_kernel(const float* __restrict__ KVp, const float* __restrict__ Ksp,
                           __bf16* __restrict__ KVT, float* __restrict__ Ks) {
    int bh = blockIdx.x, tid = threadIdx.x;
    __bf16* d = KVT + (size_t)bh * 4096;
    for (int i = tid; i < 4096; i += 256) {
        float s = 0.0f;
        #pragma unroll
        for (int c = 0; c < 8; ++c)
            s += KVp[((size_t)c * 64 + bh) * 4096 + i];
        int dk = i >> 6, dv = i & 63;
        d[dv * 64 + dk] = (__bf16)s;
    }
    if (tid < 64) {
        float s = 0.0f;
        #pragma unroll
        for (int c = 0; c < 8; ++c)
            s += Ksp[((size_t)c * 64 + bh) * 64 + tid];
        Ks[bh * 64 + tid] = s;
    }
}

// ---------------------------------------------------------------------------
// attn: On[b,t,h*64+dv] = (sum_dk Q[t,dk]*KV[dk,dv]) / (Q[t,:].Ksum + 1e-6)
// ---------------------------------------------------------------------------
__global__ __launch_bounds__(256, 2)
void attn_kernel(const __bf16* __restrict__ Qb, const __bf16* __restrict__ KVT,
                 const float* __restrict__ Ksum, __bf16* __restrict__ On)
{
    const int bh = blockIdx.y;
    const int b = bh >> 4, h = bh & 15;
    const int tc = blockIdx.x;
    const int tid = threadIdx.x, lane = tid & 63, wid = tid >> 6;
    __shared__ __bf16 kvl[64][72];
    __shared__ float dinv[256];

    {
        const int r = tid >> 2, part = tid & 3;
        const __bf16* src = KVT + (size_t)bh * 4096 + r * 64 + part * 16;
        *(bf16x8*)&kvl[r][part*16]     = *(const bf16x8*)src;
        *(bf16x8*)&kvl[r][part*16 + 8] = *(const bf16x8*)(src + 8);
    }
    {
        const int t = tc * 256 + tid;
        const __bf16* qp = Qb + ((size_t)b * T_ + t) * H_ + h * 64;
        const float* kp = Ksum + bh * 64;
        float s = 0.0f;
        #pragma unroll
        for (int i = 0; i < 8; ++i) {
            bf16x8 qv = *(const bf16x8*)(qp + i * 8);
            #pragma unroll
            for (int j = 0; j < 8; ++j) s += (float)qv[j] * kp[i*8 + j];
        }
        dinv[tid] = 1.0f / (s + 1e-6f);
    }
    __syncthreads();

    f32x4 acc[4][4];
    #pragma unroll
    for (int i = 0; i < 4; ++i)
        #pragma unroll
        for (int j = 0; j < 4; ++j) acc[i][j] = (f32x4)0.0f;

    const int t0 = tc * 256 + wid * 64;
    #pragma unroll
    for (int ks = 0; ks < 2; ++ks) {
        bf16x8 afr[4], bfr[4];
        #pragma unroll
        for (int mi = 0; mi < 4; ++mi) {
            int t = t0 + mi * 16 + (lane & 15);
            afr[mi] = *(const bf16x8*)(Qb + ((size_t)b * T_ + t) * H_ + h * 64
                                       + ks * 32 + (lane >> 4) * 8);
        }
        #pragma unroll
        for (int ni = 0; ni < 4; ++ni) {
            int dv = ni * 16 + (lane & 15);
            bfr[ni] = *(const bf16x8*)&kvl[dv][ks * 32 + (lane >> 4) * 8];
        }
        #pragma unroll
        for (int mi = 0; mi < 4; ++mi)
            #pragma unroll
            for (int ni = 0; ni < 4; ++ni)
                acc[mi][ni] = __builtin_amdgcn_mfma_f32_16x16x32_bf16(
                    afr[mi], bfr[ni], acc[mi][ni], 0, 0, 0);
    }
    #pragma unroll
    for (int mi = 0; mi < 4; ++mi)
        #pragma unroll
        for (int j = 0; j < 4; ++j) {
            int lt = wid * 64 + mi * 16 + (lane >> 4) * 4 + j;
            float z = dinv[lt];
            int t = tc * 256 + lt;
            __bf16* op = On + ((size_t)b * T_ + t) * H_ + h * 64 + (lane & 15);
            #pragma unroll
            for (int ni = 0; ni < 4; ++ni)
                op[ni * 16] = (__bf16)(acc[mi][ni][j] * z);
        }
}

// ---------------------------------------------------------------------------
extern "C" void kernel_launch(void* const* d_in, const int* in_sizes, int n_in,
                              void* d_out, int out_size, void* d_ws, size_t ws_size,
                              hipStream_t stream) {
    (void)in_sizes; (void)n_in; (void)out_size; (void)ws_size;
    const float* q    = (const float*)d_in[0];
    const float* k    = (const float*)d_in[1];
    const float* v    = (const float*)d_in[2];
    const float* mask = (const float*)d_in[3];
    const float* Wq   = (const float*)d_in[4];
    const float* Wk   = (const float*)d_in[5];
    const float* Wv   = (const float*)d_in[6];
    const float* Wo   = (const float*)d_in[7];
    float* out = (float*)d_out;

    char* ws = (char*)d_ws;
    const size_t WELEM = (size_t)H_ * H_;      // 1 Mi elems
    const size_t PELEM = (size_t)BT_ * H_;     // 32 Mi elems
    __bf16* Wqb = (__bf16*)ws;
    __bf16* Wkb = Wqb + WELEM;
    __bf16* Wvb = Wkb + WELEM;
    __bf16* Wob = Wvb + WELEM;
    __bf16* Qb  = Wob + WELEM;
    __bf16* Kb  = Qb + PELEM;
    __bf16* Vb  = Kb + PELEM;
    __bf16* tmp = Vb + PELEM;                 // conv buffer, later attn out
    float*  KVp = (float*)(tmp + PELEM);                     // 8*64*4096 f32 = 8 MB
    float*  Ksp = KVp + (size_t)8 * 64 * 4096;               // 8*64*64 f32
    float*  Ksf = Ksp + (size_t)8 * 64 * 64;                 // 64*64 f32
    __bf16* KVT = (__bf16*)(Ksf + (size_t)64 * 64);          // 64*4096 bf16
    // total ws use: ~273 MB

    wconv4<<<dim3(1024, 4), 256, 0, stream>>>(Wq, Wk, Wv, Wo, Wqb, Wkb, Wvb, Wob);

    const int cgrid = (int)(PELEM / (256 * 8));   // 16384
    conv_bf16<<<cgrid, 256, 0, stream>>>(q, tmp);
    gemm_bt<0><<<2048, 256, 0, stream>>>(tmp, Wqb, mask, Qb);
    conv_bf16<<<cgrid, 256, 0, stream>>>(k, tmp);
    gemm_bt<1><<<2048, 256, 0, stream>>>(tmp, Wkb, mask, Kb);
    conv_bf16<<<cgrid, 256, 0, stream>>>(v, tmp);
    gemm_bt<2><<<2048, 256, 0, stream>>>(tmp, Wvb, mask, Vb);

    kv_kernel<<<dim3(T_/1024, B_*NH_), 256, 0, stream>>>(Kb, Vb, KVp, Ksp);
    kvt_kernel<<<B_*NH_, 256, 0, stream>>>(KVp, Ksp, KVT, Ksf);
    attn_kernel<<<dim3(T_/256, B_*NH_), 256, 0, stream>>>(Qb, KVT, Ksf, tmp);
    gemm_bt<3><<<2048, 256, 0, stream>>>(tmp, Wob, mask, out);
}